// Round 2
// baseline (368.419 us; speedup 1.0000x reference)
//
#include <hip/hip_runtime.h>
#include <math.h>

// Problem constants (fixed by the reference).
constexpr int kN  = 250000;
constexpr int kC  = 32;
constexpr int kFC = 16;
constexpr int kFN = 16;
constexpr int kV  = 64;
constexpr int kBlock = 1024;

// Row stride of the class-vectorized LDS table, in dwords.
// Row = 32 classes * f32 = 128B, padded to 144B (16B-aligned rows; start
// bank = 4*(idx%8) -> 8 uniform start groups x 4 banks = all 32 banks).
constexpr int kRowDw = 36;

// ---------------------------------------------------------------------------
// Class-vectorized LDS log-table + log-space fast path + candidate-only
// exact fallback.
//
// LDS layout: lcat[f*64+v][c] (f32), row-padded. Per (sample, feature) a
// thread reads ONE row (its gathered v) as 8x ds_read_b128 = all 32
// classes, accumulating 32 independent per-class log-sums in registers.
// vs round-0's per-class scalar gathers: 4x fewer LDS insts, serial
// 16-add chain -> 32-way ILP.
//
// Fast path (per sample, per class):
//   T_c = K_c + sum_f Lcat[f][idx_f][c] + sum_f( -0.5*((x_f-m)*rs)^2 )
// cat log-sum is f32 adds in ascending-f order (error ~1.5e-4); gaussian
// z-form bound ~1.2e-3 (round-0-validated); total B ~<= 2e-3.
// Accept iff T_best >= -86 AND top-2 gap >= 8e-3 (= 4x bound). Otherwise
// fallback, exact-scoring ONLY candidates with T_c >= T_best - 1.6e-2
// (excluded classes provably lose). If T_best < -86 (deep underflow)
// evaluate ALL classes with the validated exact sequence (denormals /
// all-zero ties -> first max = ref semantics).
// ---------------------------------------------------------------------------

// d_ws layout (floats): [0..1023] interleaved {m, rs=1/s} per (c,f)
//                       [1024..1055] K_c          (round-0-validated prep)
__global__ __launch_bounds__(256) void nbc_prep(
    const float* __restrict__ class_probs,
    const float* __restrict__ means,
    const float* __restrict__ stds,
    float* __restrict__ ws)
{
    const int t = threadIdx.x;
    const float two_pi = 2.0f * (float)M_PI;
    for (int i = t; i < kC * kFN; i += 256) {
        float m = means[i];
        float s = stds[i];
        ws[2 * i]     = m;
        ws[2 * i + 1] = 1.0f / s;
    }
    if (t < kC) {
        float k = logf(class_probs[t]);
        for (int f = 0; f < kFN; ++f) {
            float s = stds[t * kFN + f];
            k += logf(1.0f / (two_pi * (s * s)));
        }
        ws[2 * kC * kFN + t] = k;
    }
}

__global__ __launch_bounds__(kBlock, 4) void nbc_main(
    const int*   __restrict__ X_cat,
    const float* __restrict__ X_num,
    const float* __restrict__ class_probs,
    const float* __restrict__ cat_probs,
    const float* __restrict__ means,
    const float* __restrict__ stds,
    const float* __restrict__ ws,
    int* __restrict__ out)
{
    // [f*64+v][c] log-table, 1024 rows x 36 dwords = 144 KiB.
    __shared__ float lcat[1024 * kRowDw];

    const int tid = threadIdx.x;
    const int n   = blockIdx.x * kBlock + tid;
    const bool active = (n < kN);

    // ---- issue per-sample input loads FIRST (latency hides under staging) ----
    int   idx[kFC];
    float x  [kFN];
    if (active) {
        const int4* p4 = reinterpret_cast<const int4*>(X_cat + (size_t)n * kFC);
        int4 a0 = p4[0], a1 = p4[1], a2 = p4[2], a3 = p4[3];
        idx[0]=a0.x;  idx[1]=a0.y;  idx[2]=a0.z;  idx[3]=a0.w;
        idx[4]=a1.x;  idx[5]=a1.y;  idx[6]=a1.z;  idx[7]=a1.w;
        idx[8]=a2.x;  idx[9]=a2.y;  idx[10]=a2.z; idx[11]=a2.w;
        idx[12]=a3.x; idx[13]=a3.y; idx[14]=a3.z; idx[15]=a3.w;

        const float4* q4 = reinterpret_cast<const float4*>(X_num + (size_t)n * kFN);
        float4 b0 = q4[0], b1 = q4[1], b2 = q4[2], b3 = q4[3];
        x[0]=b0.x;  x[1]=b0.y;  x[2]=b0.z;  x[3]=b0.w;
        x[4]=b1.x;  x[5]=b1.y;  x[6]=b1.z;  x[7]=b1.w;
        x[8]=b2.x;  x[9]=b2.y;  x[10]=b2.z; x[11]=b2.w;
        x[12]=b3.x; x[13]=b3.y; x[14]=b3.z; x[15]=b3.w;
    } else {
        #pragma unroll
        for (int f = 0; f < kFC; ++f) { idx[f] = 0; x[f] = 0.0f; }
    }

    // ---- stage: thread = row r=(f,v); gather its 32 classes (coalesced),
    //      logf, write as 8x aggregate-optimal ds_write_b128 ----
    {
        #pragma unroll
        for (int cg = 0; cg < 8; ++cg) {
            float4 w;
            w.x = logf(cat_probs[(size_t)(cg * 4 + 0) * 1024 + tid]);
            w.y = logf(cat_probs[(size_t)(cg * 4 + 1) * 1024 + tid]);
            w.z = logf(cat_probs[(size_t)(cg * 4 + 2) * 1024 + tid]);
            w.w = logf(cat_probs[(size_t)(cg * 4 + 3) * 1024 + tid]);
            *reinterpret_cast<float4*>(lcat + (size_t)tid * kRowDw + cg * 4) = w;
        }
    }
    __syncthreads();

    if (!active) return;

    const float2* __restrict__ P = reinterpret_cast<const float2*>(ws); // {m,rs}
    const float*  __restrict__ K = ws + 2 * kC * kFN;

    // ---- cat log-sums: 32 independent accumulators, 8x b128 per feature ----
    float acc[kC];
    #pragma unroll
    for (int c = 0; c < kC; ++c) acc[c] = 0.0f;

    #pragma unroll
    for (int f = 0; f < kFC; ++f) {
        const float4* __restrict__ R = reinterpret_cast<const float4*>(
            lcat + (size_t)((f << 6) + idx[f]) * kRowDw);
        #pragma unroll
        for (int g = 0; g < 8; ++g) {
            float4 v = R[g];
            acc[4 * g + 0] += v.x;
            acc[4 * g + 1] += v.y;
            acc[4 * g + 2] += v.z;
            acc[4 * g + 3] += v.w;
        }
    }

    // ---- gaussian + top-2 tracking ----
    float best = -INFINITY, second = -INFINITY;
    int   besti = 0;

    #pragma unroll
    for (int c = 0; c < kC; ++c) {
        float a = 0.0f;
        #pragma unroll
        for (int f = 0; f < kFN; ++f) {
            float2 p = P[(c << 4) + f];       // uniform -> scalar K$ loads
            float z = (x[f] - p.x) * p.y;
            a = fmaf(z * z, -0.5f, a);
        }
        float T = (K[c] + acc[c]) + a;
        if (T > best)        { second = best; best = T; besti = c; }
        else if (T > second) { second = T; }
    }

    if (best >= -86.0f && (best - second) >= 8.0e-3f) {
        out[n] = besti;
        return;
    }

    // ---- fallback: exact scoring of candidate classes only ----
    // thr = -inf in the deep-underflow case -> all classes exact (ref semantics).
    const float thr    = (best >= -86.0f) ? (best - 1.6e-2f) : -INFINITY;
    const float two_pi = 2.0f * (float)M_PI;
    float bb = -INFINITY;
    int   bi = 0;

    #pragma unroll 2
    for (int c = 0; c < kC; ++c) {
        // Recompute T_c from the LIVE register log-sum (no LDS, no re-gather).
        float a = 0.0f;
        #pragma unroll
        for (int f = 0; f < kFN; ++f) {
            float2 p = P[(c << 4) + f];
            float z = (x[f] - p.x) * p.y;
            a = fmaf(z * z, -0.5f, a);
        }
        float T = (K[c] + acc[c]) + a;

        if (T >= thr) {
            // Exact reference numerics (validated, bit-identical sequence).
            const float* __restrict__ row = cat_probs + (size_t)c * (kFC * kV);
            float cat = row[idx[0]];
            #pragma unroll
            for (int f = 1; f < kFC; ++f) {
                cat *= row[(f << 6) + idx[f]];
            }
            float num;
            #pragma unroll
            for (int f = 0; f < kFN; ++f) {
                float m = means[c * kFN + f];
                float s = stds [c * kFN + f];
                float inv = 1.0f / (two_pi * (s * s));
                float z = (x[f] - m) / s;              // IEEE divide
                float e = expf(-0.5f * (z * z));
                float lik = inv * e;
                num = (f == 0) ? lik : num * lik;
            }
            float pred = (class_probs[c] * cat) * num; // ((cp*cat)*num) like ref
            if (pred > bb) { bb = pred; bi = c; }      // strict > -> first max
        }
    }
    out[n] = bi;
}

extern "C" void kernel_launch(void* const* d_in, const int* in_sizes, int n_in,
                              void* d_out, int out_size, void* d_ws, size_t ws_size,
                              hipStream_t stream) {
    const int*   X_cat       = (const int*)  d_in[0];
    const float* X_num       = (const float*)d_in[1];
    const float* class_probs = (const float*)d_in[2];
    const float* cat_probs   = (const float*)d_in[3];
    const float* means       = (const float*)d_in[4];
    const float* stds        = (const float*)d_in[5];
    int*   out = (int*)d_out;
    float* ws  = (float*)d_ws;   // 4224 bytes used

    hipLaunchKernelGGL(nbc_prep, dim3(1), dim3(256), 0, stream,
                       class_probs, means, stds, ws);

    dim3 block(kBlock);
    dim3 grid((kN + kBlock - 1) / kBlock);
    hipLaunchKernelGGL(nbc_main, grid, block, 0, stream,
                       X_cat, X_num, class_probs, cat_probs, means, stds, ws, out);
}

// Round 3
// 348.903 us; speedup vs baseline: 1.0559x; 1.0559x over previous
//
#include <hip/hip_runtime.h>
#include <math.h>

// Problem constants (fixed by the reference).
constexpr int kN  = 250000;
constexpr int kC  = 32;
constexpr int kFC = 16;
constexpr int kFN = 16;
constexpr int kV  = 64;
constexpr int kBlock = 1024;

// Row stride of the class-vectorized LDS table, in dwords.
// Row = 32 classes * f32 = 128B, padded to 144B (16B-aligned rows; start
// bank = 4*(row%8) -> 8 uniform start groups x 4 banks = all 32 banks;
// round-2 measured: conflicts 2.9M total = ~0.09 extra cyc/inst, fine).
constexpr int kRowDw = 36;

// ws layout (dwords): [0..1023]   {m, A=-0.5/s^2} interleaved per (c,f)
//                     [1024..1055] K_c
//                     [1088..33855] ltab[r=(f,v)][c] = logf(cat_probs[c][r])
constexpr int    kTabOffDw   = 1088;                       // byte 4352, 16B aligned
constexpr size_t kWsNeedBytes = (size_t)(kTabOffDw + 1024 * kC) * 4;  // 135424

// ---------------------------------------------------------------------------
// Class-vectorized LDS log-table, TWO half-class passes (acc[16] keeps the
// kernel inside the observed 64-VGPR budget -- round 2's acc[32] spilled to
// scratch: 431 MB WRITE_SIZE), candidate-only exact fallback.
//
// Fast path (per sample, per class):
//   T_c = K_c + sum_f Lcat[f][idx_f][c] + sum_f A_cf*(x_f - m_cf)^2
// cat log-sum: f32 adds ascending f from 0.0f (error ~1.5e-4); gaussian
// d-form bound ~1.2e-3; total B ~<= 2e-3.
// Accept iff T_best >= -86 AND top-2 gap >= 8e-3 (= 4x bound). Otherwise
// fallback, exact-scoring ONLY candidates with T_c >= T_best - 1.6e-2
// (excluded classes provably lose: true log-score <= T_c + 2e-3 <=
// best - 1.4e-2 < best - 2e-3 <= true best). T recompute in the fallback
// uses the same op order -> bit-identical to the fast path. If
// T_best < -86 (deep underflow) evaluate ALL classes with the validated
// exact sequence (denormals / all-zero ties -> first max = ref semantics).
// ---------------------------------------------------------------------------

__global__ __launch_bounds__(256) void nbc_prep(
    const float* __restrict__ class_probs,
    const float* __restrict__ means,
    const float* __restrict__ stds,
    const float* __restrict__ cat_probs,
    float* __restrict__ ws,
    int use_tab)
{
    const int b = blockIdx.x;
    const int t = threadIdx.x;
    if (b == 0) {
        const float two_pi = 2.0f * (float)M_PI;
        for (int i = t; i < kC * kFN; i += 256) {
            float m = means[i];
            float s = stds[i];
            ws[2 * i]     = m;
            ws[2 * i + 1] = -0.5f / (s * s);        // A
        }
        if (t < kC) {
            float k = logf(class_probs[t]);
            for (int f = 0; f < kFN; ++f) {
                float s = stds[t * kFN + f];
                k += logf(1.0f / (two_pi * (s * s)));
            }
            ws[1024 + t] = k;
        }
    } else if (use_tab) {
        // blocks 1..32: transpose-log 1024 source elements each.
        // s = c*1024 + r (source-linear, coalesced reads) -> ltab[r*32 + c].
        const int base = (b - 1) * 1024;
        for (int k2 = 0; k2 < 4; ++k2) {
            int s = base + t + k2 * 256;
            int c = s >> 10;
            int r = s & 1023;
            ws[kTabOffDw + r * 32 + c] = logf(cat_probs[s]);
        }
    }
}

__global__ __launch_bounds__(kBlock, 2) void nbc_main(
    const int*   __restrict__ X_cat,
    const float* __restrict__ X_num,
    const float* __restrict__ class_probs,
    const float* __restrict__ cat_probs,
    const float* __restrict__ means,
    const float* __restrict__ stds,
    const float* __restrict__ ws,
    int* __restrict__ out,
    int use_tab)
{
    // [r=(f,v)][c] log-table, 1024 rows x 36 dwords = 144 KiB.
    __shared__ float lcat[1024 * kRowDw];

    const int tid = threadIdx.x;
    const int n   = blockIdx.x * kBlock + tid;
    const bool active = (n < kN);

    // ---- issue per-sample input loads FIRST (latency hides under staging) ----
    int   idx[kFC];
    float x  [kFN];
    if (active) {
        const int4* p4 = reinterpret_cast<const int4*>(X_cat + (size_t)n * kFC);
        int4 a0 = p4[0], a1 = p4[1], a2 = p4[2], a3 = p4[3];
        idx[0]=a0.x;  idx[1]=a0.y;  idx[2]=a0.z;  idx[3]=a0.w;
        idx[4]=a1.x;  idx[5]=a1.y;  idx[6]=a1.z;  idx[7]=a1.w;
        idx[8]=a2.x;  idx[9]=a2.y;  idx[10]=a2.z; idx[11]=a2.w;
        idx[12]=a3.x; idx[13]=a3.y; idx[14]=a3.z; idx[15]=a3.w;

        const float4* q4 = reinterpret_cast<const float4*>(X_num + (size_t)n * kFN);
        float4 b0 = q4[0], b1 = q4[1], b2 = q4[2], b3 = q4[3];
        x[0]=b0.x;  x[1]=b0.y;  x[2]=b0.z;  x[3]=b0.w;
        x[4]=b1.x;  x[5]=b1.y;  x[6]=b1.z;  x[7]=b1.w;
        x[8]=b2.x;  x[9]=b2.y;  x[10]=b2.z; x[11]=b2.w;
        x[12]=b3.x; x[13]=b3.y; x[14]=b3.z; x[15]=b3.w;
    } else {
        #pragma unroll
        for (int f = 0; f < kFC; ++f) { idx[f] = 0; x[f] = 0.0f; }
    }

    // ---- stage the log-table into LDS ----
    if (use_tab) {
        // pure copy: 8x (coalesced float4 load + ds_write_b128) per thread
        const float4* __restrict__ lt4 =
            reinterpret_cast<const float4*>(ws + kTabOffDw);
        #pragma unroll
        for (int i = 0; i < 8; ++i) {
            int j = i * kBlock + tid;          // chunk 0..8191
            float4 w = lt4[j];
            int r  = j >> 3;
            int cg = j & 7;
            *reinterpret_cast<float4*>(lcat + r * kRowDw + cg * 4) = w;
        }
    } else {
        // validated round-2 path: gather + logf in-kernel
        #pragma unroll
        for (int cg = 0; cg < 8; ++cg) {
            float4 w;
            w.x = logf(cat_probs[(size_t)(cg * 4 + 0) * 1024 + tid]);
            w.y = logf(cat_probs[(size_t)(cg * 4 + 1) * 1024 + tid]);
            w.z = logf(cat_probs[(size_t)(cg * 4 + 2) * 1024 + tid]);
            w.w = logf(cat_probs[(size_t)(cg * 4 + 3) * 1024 + tid]);
            *reinterpret_cast<float4*>(lcat + (size_t)tid * kRowDw + cg * 4) = w;
        }
    }
    __syncthreads();

    if (!active) return;

    // Row dword-offsets; idx[] is dead after this (fallback recovers
    // (f<<6)+idx_f as rowd[f]/36) -> lower peak register pressure.
    int rowd[kFC];
    #pragma unroll
    for (int f = 0; f < kFC; ++f) rowd[f] = ((f << 6) + idx[f]) * kRowDw;

    const float2* __restrict__ P = reinterpret_cast<const float2*>(ws); // {m,A}
    const float*  __restrict__ K = ws + 1024;

    float best = -INFINITY, second = -INFINITY;
    int   besti = 0;

    // ---- two half-class passes: acc[16] stays in registers ----
    #pragma unroll
    for (int h = 0; h < 2; ++h) {
        float acc[16];
        #pragma unroll
        for (int j = 0; j < 16; ++j) acc[j] = 0.0f;

        #pragma unroll
        for (int f = 0; f < kFC; ++f) {
            const float4* __restrict__ R =
                reinterpret_cast<const float4*>(lcat + rowd[f]) + h * 4;
            #pragma unroll
            for (int g = 0; g < 4; ++g) {
                float4 v = R[g];
                acc[4 * g + 0] += v.x;
                acc[4 * g + 1] += v.y;
                acc[4 * g + 2] += v.z;
                acc[4 * g + 3] += v.w;
            }
        }

        #pragma unroll
        for (int j = 0; j < 16; ++j) {
            const int c = h * 16 + j;
            float a = 0.0f;
            #pragma unroll
            for (int f = 0; f < kFN; ++f) {
                float2 p = P[(c << 4) + f];     // uniform -> scalar K$ loads
                float d = x[f] - p.x;
                a = fmaf(d * d, p.y, a);
            }
            float T = (K[c] + acc[j]) + a;
            if (T > best)        { second = best; best = T; besti = c; }
            else if (T > second) { second = T; }
        }
    }

    if (best >= -86.0f && (best - second) >= 8.0e-3f) {
        out[n] = besti;
        return;
    }

    // ---- fallback: exact scoring of candidate classes only (rare) ----
    const float thr    = (best >= -86.0f) ? (best - 1.6e-2f) : -INFINITY;
    const float two_pi = 2.0f * (float)M_PI;
    float bb = -INFINITY;
    int   bi = 0;

    for (int c = 0; c < kC; ++c) {
        // Recompute T_c with the SAME op order as the fast path (bit-identical).
        float lc = 0.0f;
        #pragma unroll
        for (int f = 0; f < kFC; ++f) lc += lcat[rowd[f] + c];
        float a = 0.0f;
        #pragma unroll
        for (int f = 0; f < kFN; ++f) {
            float2 p = P[(c << 4) + f];
            float d = x[f] - p.x;
            a = fmaf(d * d, p.y, a);
        }
        float T = (K[c] + lc) + a;

        if (T >= thr) {
            // Exact reference numerics (validated, bit-identical sequence).
            const float* __restrict__ row = cat_probs + (size_t)c * (kFC * kV);
            float cat = row[rowd[0] / kRowDw];
            #pragma unroll
            for (int f = 1; f < kFC; ++f) {
                cat *= row[rowd[f] / kRowDw];   // rowd[f]/36 == (f<<6)+idx[f]
            }
            float num;
            #pragma unroll
            for (int f = 0; f < kFN; ++f) {
                float m = means[c * kFN + f];
                float s = stds [c * kFN + f];
                float inv = 1.0f / (two_pi * (s * s));
                float z = (x[f] - m) / s;              // IEEE divide
                float e = expf(-0.5f * (z * z));
                float lik = inv * e;
                num = (f == 0) ? lik : num * lik;
            }
            float pred = (class_probs[c] * cat) * num; // ((cp*cat)*num) like ref
            if (pred > bb) { bb = pred; bi = c; }      // strict > -> first max
        }
    }
    out[n] = bi;
}

extern "C" void kernel_launch(void* const* d_in, const int* in_sizes, int n_in,
                              void* d_out, int out_size, void* d_ws, size_t ws_size,
                              hipStream_t stream) {
    const int*   X_cat       = (const int*)  d_in[0];
    const float* X_num       = (const float*)d_in[1];
    const float* class_probs = (const float*)d_in[2];
    const float* cat_probs   = (const float*)d_in[3];
    const float* means       = (const float*)d_in[4];
    const float* stds        = (const float*)d_in[5];
    int*   out = (int*)d_out;
    float* ws  = (float*)d_ws;

    const int use_tab = (ws_size >= kWsNeedBytes) ? 1 : 0;

    hipLaunchKernelGGL(nbc_prep, dim3(use_tab ? 33 : 1), dim3(256), 0, stream,
                       class_probs, means, stds, cat_probs, ws, use_tab);

    dim3 block(kBlock);
    dim3 grid((kN + kBlock - 1) / kBlock);
    hipLaunchKernelGGL(nbc_main, grid, block, 0, stream,
                       X_cat, X_num, class_probs, cat_probs, means, stds, ws,
                       out, use_tab);
}

// Round 4
// 344.471 us; speedup vs baseline: 1.0695x; 1.0129x over previous
//
#include <hip/hip_runtime.h>
#include <math.h>

// Problem constants (fixed by the reference).
constexpr int kN  = 250000;
constexpr int kC  = 32;
constexpr int kFC = 16;
constexpr int kFN = 16;
constexpr int kV  = 64;
constexpr int kBlock = 1024;

// Row stride of the class-vectorized LDS table, in dwords.
// Row = 32 classes * f32 = 128B, padded to 144B (16B-aligned rows; start
// bank = 4*(row%8) -> 8 uniform start groups x 4 banks = all 32 banks;
// measured round 2/3: ~2.9M conflict-cycles total = negligible).
constexpr int kRowDw = 36;

// ws layout (dwords): [0..1023]   {m, A=-0.5/s^2} interleaved per (c,f)
//                     [1024..1055] K_c
//                     [1088..33855] ltab[r=(f,v)][c] = logf(cat_probs[c][r])
constexpr int    kTabOffDw    = 1088;                      // byte 4352, 16B aligned
constexpr size_t kWsNeedBytes = (size_t)(kTabOffDw + 1024 * kC) * 4;  // 135424

// ---------------------------------------------------------------------------
// Class-vectorized LDS log-table; TWO GENUINE half-class passes.
//
// Rounds 2/3 spilled acc to scratch (431/342 MB WRITE_SIZE, occupancy
// 0.7%): '#pragma unroll' on the half loop merged both halves' register
// lifetimes (= acc[32] again) inside the compiler's 64-VGPR budget.
// This version forces '#pragma unroll 1' on the half loop and packs the
// 16 categorical indices into 4 dwords (byte fields), so peak live state
// is x[16]+acc[16]+pack[4] ~= 36 regs + temps.
//
// Fast path (per sample, per class), op order (fallback mirrors it):
//   a = K_c; for f: a = fma(d_f^2, A_cf, a)   (d = x_f - m_cf)
//   for f ascending: a += Lcat[f][idx_f][c]
// Total approx-vs-truth bound B ~<= 2e-3 (gauss ~1.2e-3, log-sum ~1.5e-4,
// table logf 1-ulp, K rounding).
// Accept iff T_best >= -86 AND top-2 gap >= 8e-3 (>= 4x bound). Otherwise
// fallback, exact-scoring ONLY candidates with T_c >= T_best - 1.6e-2
// (excluded classes provably lose: true <= T_c + B <= best - 1.4e-2 <
// best - B <= true best). If T_best < -86 (deep underflow) evaluate ALL
// classes with the validated exact sequence (denormals / all-zero ties ->
// first max = ref semantics).
// ---------------------------------------------------------------------------

__global__ __launch_bounds__(256) void nbc_prep(
    const float* __restrict__ class_probs,
    const float* __restrict__ means,
    const float* __restrict__ stds,
    const float* __restrict__ cat_probs,
    float* __restrict__ ws,
    int use_tab)
{
    const int b = blockIdx.x;
    const int t = threadIdx.x;
    if (b == 0) {
        const float two_pi = 2.0f * (float)M_PI;
        for (int i = t; i < kC * kFN; i += 256) {
            float m = means[i];
            float s = stds[i];
            ws[2 * i]     = m;
            ws[2 * i + 1] = -0.5f / (s * s);        // A
        }
        if (t < kC) {
            float k = logf(class_probs[t]);
            for (int f = 0; f < kFN; ++f) {
                float s = stds[t * kFN + f];
                k += logf(1.0f / (two_pi * (s * s)));
            }
            ws[1024 + t] = k;
        }
    } else if (use_tab) {
        // blocks 1..32: transpose-log 1024 source elements each.
        // s = c*1024 + r (source-linear, coalesced reads) -> ltab[r*32 + c].
        const int base = (b - 1) * 1024;
        for (int k2 = 0; k2 < 4; ++k2) {
            int s = base + t + k2 * 256;
            int c = s >> 10;
            int r = s & 1023;
            ws[kTabOffDw + r * 32 + c] = logf(cat_probs[s]);
        }
    }
}

__global__ __launch_bounds__(kBlock) void nbc_main(
    const int*   __restrict__ X_cat,
    const float* __restrict__ X_num,
    const float* __restrict__ class_probs,
    const float* __restrict__ cat_probs,
    const float* __restrict__ means,
    const float* __restrict__ stds,
    const float* __restrict__ ws,
    int* __restrict__ out,
    int use_tab)
{
    // [r=(f,v)][c] log-table, 1024 rows x 36 dwords = 144 KiB.
    __shared__ float lcat[1024 * kRowDw];

    const int tid = threadIdx.x;
    const int n   = blockIdx.x * kBlock + tid;
    const bool active = (n < kN);

    // ---- per-sample inputs first (latency hides under staging) ----
    // 16 categorical indices (0..63) packed as byte fields into 4 dwords.
    unsigned pack[4];
    float    x[kFN];
    if (active) {
        const int4* p4 = reinterpret_cast<const int4*>(X_cat + (size_t)n * kFC);
        int4 a0 = p4[0], a1 = p4[1], a2 = p4[2], a3 = p4[3];
        pack[0] = (unsigned)a0.x | ((unsigned)a0.y << 8) |
                  ((unsigned)a0.z << 16) | ((unsigned)a0.w << 24);
        pack[1] = (unsigned)a1.x | ((unsigned)a1.y << 8) |
                  ((unsigned)a1.z << 16) | ((unsigned)a1.w << 24);
        pack[2] = (unsigned)a2.x | ((unsigned)a2.y << 8) |
                  ((unsigned)a2.z << 16) | ((unsigned)a2.w << 24);
        pack[3] = (unsigned)a3.x | ((unsigned)a3.y << 8) |
                  ((unsigned)a3.z << 16) | ((unsigned)a3.w << 24);

        const float4* q4 = reinterpret_cast<const float4*>(X_num + (size_t)n * kFN);
        float4 b0 = q4[0], b1 = q4[1], b2 = q4[2], b3 = q4[3];
        x[0]=b0.x;  x[1]=b0.y;  x[2]=b0.z;  x[3]=b0.w;
        x[4]=b1.x;  x[5]=b1.y;  x[6]=b1.z;  x[7]=b1.w;
        x[8]=b2.x;  x[9]=b2.y;  x[10]=b2.z; x[11]=b2.w;
        x[12]=b3.x; x[13]=b3.y; x[14]=b3.z; x[15]=b3.w;
    } else {
        pack[0] = pack[1] = pack[2] = pack[3] = 0u;
        #pragma unroll
        for (int f = 0; f < kFN; ++f) x[f] = 0.0f;
    }

    // ---- stage the log-table into LDS ----
    if (use_tab) {
        // pure copy: 8x (coalesced float4 load + ds_write_b128) per thread
        const float4* __restrict__ lt4 =
            reinterpret_cast<const float4*>(ws + kTabOffDw);
        #pragma unroll
        for (int i = 0; i < 8; ++i) {
            int j = i * kBlock + tid;          // chunk 0..8191
            float4 w = lt4[j];
            int r  = j >> 3;
            int cg = j & 7;
            *reinterpret_cast<float4*>(lcat + r * kRowDw + cg * 4) = w;
        }
    } else {
        // validated fallback staging: gather + logf in-kernel
        #pragma unroll
        for (int cg = 0; cg < 8; ++cg) {
            float4 w;
            w.x = logf(cat_probs[(size_t)(cg * 4 + 0) * 1024 + tid]);
            w.y = logf(cat_probs[(size_t)(cg * 4 + 1) * 1024 + tid]);
            w.z = logf(cat_probs[(size_t)(cg * 4 + 2) * 1024 + tid]);
            w.w = logf(cat_probs[(size_t)(cg * 4 + 3) * 1024 + tid]);
            *reinterpret_cast<float4*>(lcat + (size_t)tid * kRowDw + cg * 4) = w;
        }
    }
    __syncthreads();

    if (!active) return;

    const float2* __restrict__ P = reinterpret_cast<const float2*>(ws); // {m,A}
    const float*  __restrict__ K = ws + 1024;

    float best = -INFINITY, second = -INFINITY;
    int   besti = 0;

    // ---- two GENUINE half-class passes (NOT unrolled: one acc[16] live) ----
    #pragma unroll 1
    for (int h = 0; h < 2; ++h) {
        float acc[16];

        // gaussian first, K folded into the fma chain
        #pragma unroll
        for (int j = 0; j < 16; ++j) {
            const int c = (h << 4) + j;         // wave-uniform -> scalar loads
            float a = K[c];
            #pragma unroll
            for (int f = 0; f < kFN; ++f) {
                float2 p = P[(c << 4) + f];
                float d = x[f] - p.x;
                a = fmaf(d * d, p.y, a);
            }
            acc[j] = a;
        }

        // categorical log-sums: 4x ds_read_b128 per feature (16 classes)
        #pragma unroll
        for (int f = 0; f < kFC; ++f) {
            const int v = (pack[f >> 2] >> ((f & 3) * 8)) & 63;
            const float4* __restrict__ R = reinterpret_cast<const float4*>(
                lcat + ((f << 6) + v) * kRowDw) + (h << 2);
            #pragma unroll
            for (int g = 0; g < 4; ++g) {
                float4 t = R[g];
                acc[4 * g + 0] += t.x;
                acc[4 * g + 1] += t.y;
                acc[4 * g + 2] += t.z;
                acc[4 * g + 3] += t.w;
            }
        }

        // top-2 tracking
        #pragma unroll
        for (int j = 0; j < 16; ++j) {
            float T = acc[j];
            if (T > best)        { second = best; best = T; besti = (h << 4) + j; }
            else if (T > second) { second = T; }
        }
    }

    if (best >= -86.0f && (best - second) >= 8.0e-3f) {
        out[n] = besti;
        return;
    }

    // ---- fallback: exact scoring of candidate classes only (rare) ----
    const float thr    = (best >= -86.0f) ? (best - 1.6e-2f) : -INFINITY;
    const float two_pi = 2.0f * (float)M_PI;
    float bb = -INFINITY;
    int   bi = 0;

    for (int c = 0; c < kC; ++c) {
        // Recompute T_c with the SAME op order as the fast path.
        float a = K[c];
        #pragma unroll
        for (int f = 0; f < kFN; ++f) {
            float2 p = P[(c << 4) + f];
            float d = x[f] - p.x;
            a = fmaf(d * d, p.y, a);
        }
        #pragma unroll
        for (int f = 0; f < kFC; ++f) {
            const int v = (pack[f >> 2] >> ((f & 3) * 8)) & 63;
            a += lcat[((f << 6) + v) * kRowDw + c];
        }

        if (a >= thr) {
            // Exact reference numerics (validated, bit-identical sequence).
            const float* __restrict__ row = cat_probs + (size_t)c * (kFC * kV);
            float cat = row[pack[0] & 63];
            #pragma unroll
            for (int f = 1; f < kFC; ++f) {
                const int v = (pack[f >> 2] >> ((f & 3) * 8)) & 63;
                cat *= row[(f << 6) + v];
            }
            float num;
            #pragma unroll
            for (int f = 0; f < kFN; ++f) {
                float m = means[c * kFN + f];
                float s = stds [c * kFN + f];
                float inv = 1.0f / (two_pi * (s * s));
                float z = (x[f] - m) / s;              // IEEE divide
                float e = expf(-0.5f * (z * z));
                float lik = inv * e;
                num = (f == 0) ? lik : num * lik;
            }
            float pred = (class_probs[c] * cat) * num; // ((cp*cat)*num) like ref
            if (pred > bb) { bb = pred; bi = c; }      // strict > -> first max
        }
    }
    out[n] = bi;
}

extern "C" void kernel_launch(void* const* d_in, const int* in_sizes, int n_in,
                              void* d_out, int out_size, void* d_ws, size_t ws_size,
                              hipStream_t stream) {
    const int*   X_cat       = (const int*)  d_in[0];
    const float* X_num       = (const float*)d_in[1];
    const float* class_probs = (const float*)d_in[2];
    const float* cat_probs   = (const float*)d_in[3];
    const float* means       = (const float*)d_in[4];
    const float* stds        = (const float*)d_in[5];
    int*   out = (int*)d_out;
    float* ws  = (float*)d_ws;

    const int use_tab = (ws_size >= kWsNeedBytes) ? 1 : 0;

    hipLaunchKernelGGL(nbc_prep, dim3(use_tab ? 33 : 1), dim3(256), 0, stream,
                       class_probs, means, stds, cat_probs, ws, use_tab);

    dim3 block(kBlock);
    dim3 grid((kN + kBlock - 1) / kBlock);
    hipLaunchKernelGGL(nbc_main, grid, block, 0, stream,
                       X_cat, X_num, class_probs, cat_probs, means, stds, ws,
                       out, use_tab);
}

// Round 5
// 138.153 us; speedup vs baseline: 2.6667x; 2.4934x over previous
//
#include <hip/hip_runtime.h>
#include <math.h>

// Problem constants (fixed by the reference).
constexpr int kN  = 250000;
constexpr int kC  = 32;
constexpr int kFC = 16;
constexpr int kFN = 16;
constexpr int kV  = 64;
constexpr int kBlock = 1024;

// Row stride of the class-vectorized LDS table, in dwords.
// Row = 32 classes * f32 = 128B, padded to 144B. 16B-aligned rows; b128
// start bank = 4*((v + grp) % 8)*... -> 8 distinct 16B slots across lanes.
// Measured (rounds 2-4): ~2.9M conflict-cycles total = negligible.
constexpr int kRowDw = 36;

// ws layout (dwords): [0..1023]   {A=-0.5/s^2, B=m/s^2} interleaved per (c,f)
//                     [1024..1055] K_c  (incl. folded C = -0.5 m^2/s^2 terms)
//                     [1088..33855] ltab[r=(f,v)][c] = logf(cat_probs[c][r])
constexpr int    kTabOffDw    = 1088;                      // byte 4352, 16B aligned
constexpr size_t kWsNeedBytes = (size_t)(kTabOffDw + 1024 * kC) * 4;  // 135424

// ---------------------------------------------------------------------------
// Class-GROUP-of-4 structure. Rounds 2-4 all spilled (342-431 MB scratch
// WRITE_SIZE): with 1024-thread blocks the compiler pins a 64-VGPR budget
// and acc[16]+x[16] exceeds it regardless of loop phrasing. This version
// needs only acc[4] live at a time: per class-group, ONE ds_read_b128 per
// feature delivers that group's 4 classes; accumulators die into the
// running top-2 before the next group. Peak live ~= x[16] + rowdw[16] +
// pack[4] + acc[4] + top-2 ~= 45 regs < round 1's (non-spilling) set.
//
// Fast path (per sample, per class), op order (fallback mirrors exactly):
//   a = K_c
//   for f ascending: a = fma(x_f, fma(x_f, A_cf, B_cf), a)   (quad form)
//   for f ascending: a += Lcat[f][idx_f][c]
// Approx-vs-truth bound B ~<= 2e-3 (accumulation-dominated; quad-form
// cancellation adds ~3e-5). Accept iff T_best >= -86 AND top-2 gap >=
// 8e-3 (>= 4x bound). Otherwise fallback, exact-scoring ONLY candidates
// with T_c >= T_best - 1.6e-2 (excluded classes provably lose: true <=
// T_c + B <= best - 1.4e-2 < best - B <= true best). If T_best < -86
// (deep underflow) evaluate ALL classes with the validated exact sequence
// (denormals / all-zero ties -> first max = ref semantics).
// ---------------------------------------------------------------------------

__global__ __launch_bounds__(256) void nbc_prep(
    const float* __restrict__ class_probs,
    const float* __restrict__ means,
    const float* __restrict__ stds,
    const float* __restrict__ cat_probs,
    float* __restrict__ ws,
    int use_tab)
{
    const int b = blockIdx.x;
    const int t = threadIdx.x;
    if (b == 0) {
        const float two_pi = 2.0f * (float)M_PI;
        for (int i = t; i < kC * kFN; i += 256) {
            float m  = means[i];
            float s  = stds[i];
            float rs = 1.0f / s;
            ws[2 * i]     = -0.5f * rs * rs;        // A
            ws[2 * i + 1] = m * rs * rs;            // B
        }
        if (t < kC) {
            float k = logf(class_probs[t]);
            for (int f = 0; f < kFN; ++f) {
                float s  = stds[t * kFN + f];
                float m  = means[t * kFN + f];
                float rs = 1.0f / s;
                k += logf(1.0f / (two_pi * (s * s)));
                k += -0.5f * (m * rs) * (m * rs);   // C folded into K
            }
            ws[1024 + t] = k;
        }
    } else if (use_tab) {
        // blocks 1..32: transpose-log 1024 source elements each.
        // s = c*1024 + r (source-linear, coalesced reads) -> ltab[r*32 + c].
        const int base = (b - 1) * 1024;
        for (int k2 = 0; k2 < 4; ++k2) {
            int s = base + t + k2 * 256;
            int c = s >> 10;
            int r = s & 1023;
            ws[kTabOffDw + r * 32 + c] = logf(cat_probs[s]);
        }
    }
}

__global__ __launch_bounds__(kBlock) void nbc_main(
    const int*   __restrict__ X_cat,
    const float* __restrict__ X_num,
    const float* __restrict__ class_probs,
    const float* __restrict__ cat_probs,
    const float* __restrict__ means,
    const float* __restrict__ stds,
    const float* __restrict__ ws,
    int* __restrict__ out,
    int use_tab)
{
    // [r=(f,v)][c] log-table, 1024 rows x 36 dwords = 144 KiB.
    __shared__ float lcat[1024 * kRowDw];

    const int tid = threadIdx.x;
    const int n   = blockIdx.x * kBlock + tid;
    const bool active = (n < kN);

    // ---- per-sample inputs first (latency hides under staging) ----
    unsigned pack[4];           // 16 six-bit indices, byte fields
    float    x[kFN];
    if (active) {
        const int4* p4 = reinterpret_cast<const int4*>(X_cat + (size_t)n * kFC);
        int4 a0 = p4[0], a1 = p4[1], a2 = p4[2], a3 = p4[3];
        pack[0] = (unsigned)a0.x | ((unsigned)a0.y << 8) |
                  ((unsigned)a0.z << 16) | ((unsigned)a0.w << 24);
        pack[1] = (unsigned)a1.x | ((unsigned)a1.y << 8) |
                  ((unsigned)a1.z << 16) | ((unsigned)a1.w << 24);
        pack[2] = (unsigned)a2.x | ((unsigned)a2.y << 8) |
                  ((unsigned)a2.z << 16) | ((unsigned)a2.w << 24);
        pack[3] = (unsigned)a3.x | ((unsigned)a3.y << 8) |
                  ((unsigned)a3.z << 16) | ((unsigned)a3.w << 24);

        const float4* q4 = reinterpret_cast<const float4*>(X_num + (size_t)n * kFN);
        float4 b0 = q4[0], b1 = q4[1], b2 = q4[2], b3 = q4[3];
        x[0]=b0.x;  x[1]=b0.y;  x[2]=b0.z;  x[3]=b0.w;
        x[4]=b1.x;  x[5]=b1.y;  x[6]=b1.z;  x[7]=b1.w;
        x[8]=b2.x;  x[9]=b2.y;  x[10]=b2.z; x[11]=b2.w;
        x[12]=b3.x; x[13]=b3.y; x[14]=b3.z; x[15]=b3.w;
    } else {
        pack[0] = pack[1] = pack[2] = pack[3] = 0u;
        #pragma unroll
        for (int f = 0; f < kFN; ++f) x[f] = 0.0f;
    }

    // ---- stage the log-table into LDS ----
    if (use_tab) {
        // pure copy: 8x (coalesced float4 load + ds_write_b128) per thread
        const float4* __restrict__ lt4 =
            reinterpret_cast<const float4*>(ws + kTabOffDw);
        #pragma unroll
        for (int i = 0; i < 8; ++i) {
            int j = i * kBlock + tid;          // chunk 0..8191
            float4 w = lt4[j];
            int r  = j >> 3;
            int cg = j & 7;
            *reinterpret_cast<float4*>(lcat + r * kRowDw + cg * 4) = w;
        }
    } else {
        // validated fallback staging: gather + logf in-kernel
        #pragma unroll
        for (int cg = 0; cg < 8; ++cg) {
            float4 w;
            w.x = logf(cat_probs[(size_t)(cg * 4 + 0) * 1024 + tid]);
            w.y = logf(cat_probs[(size_t)(cg * 4 + 1) * 1024 + tid]);
            w.z = logf(cat_probs[(size_t)(cg * 4 + 2) * 1024 + tid]);
            w.w = logf(cat_probs[(size_t)(cg * 4 + 3) * 1024 + tid]);
            *reinterpret_cast<float4*>(lcat + (size_t)tid * kRowDw + cg * 4) = w;
        }
    }
    __syncthreads();

    if (!active) return;

    // Per-feature row base (dword offset into lcat); group adds (grp<<2).
    int rowdw[kFC];
    #pragma unroll
    for (int f = 0; f < kFC; ++f) {
        const int v = (pack[f >> 2] >> ((f & 3) * 8)) & 63;
        rowdw[f] = ((f << 6) + v) * kRowDw;
    }

    const float2* __restrict__ P = reinterpret_cast<const float2*>(ws); // {A,B}
    const float*  __restrict__ K = ws + 1024;

    float best = -INFINITY, second = -INFINITY;
    int   besti = 0;

    // ---- 8 class-groups of 4; only acc[4] live at a time ----
    #pragma unroll 1
    for (int grp = 0; grp < 8; ++grp) {
        const int cbase = grp << 2;
        float acc[4];

        // K + gaussian (quadratic form), f ascending
        #pragma unroll
        for (int j = 0; j < 4; ++j) {
            const int c = cbase + j;            // wave-uniform -> scalar loads
            float a = K[c];
            #pragma unroll
            for (int f = 0; f < kFN; ++f) {
                float2 p = P[(c << 4) + f];
                a = fmaf(x[f], fmaf(x[f], p.x, p.y), a);
            }
            acc[j] = a;
        }

        // categorical log-adds: ONE ds_read_b128 per feature = 4 classes
        #pragma unroll
        for (int f = 0; f < kFC; ++f) {
            const float4 t = *reinterpret_cast<const float4*>(
                &lcat[rowdw[f] + (grp << 2)]);
            acc[0] += t.x;
            acc[1] += t.y;
            acc[2] += t.z;
            acc[3] += t.w;
        }

        // top-2 tracking (accs die here)
        #pragma unroll
        for (int j = 0; j < 4; ++j) {
            float T = acc[j];
            if (T > best)        { second = best; best = T; besti = cbase + j; }
            else if (T > second) { second = T; }
        }
    }

    if (best >= -86.0f && (best - second) >= 8.0e-3f) {
        out[n] = besti;
        return;
    }

    // ---- fallback: exact scoring of candidate classes only (rare) ----
    const float thr    = (best >= -86.0f) ? (best - 1.6e-2f) : -INFINITY;
    const float two_pi = 2.0f * (float)M_PI;
    float bb = -INFINITY;
    int   bi = 0;

    for (int c = 0; c < kC; ++c) {
        // Recompute T_c with the SAME op order as the fast path (bit-identical).
        float a = K[c];
        #pragma unroll
        for (int f = 0; f < kFN; ++f) {
            float2 p = P[(c << 4) + f];
            a = fmaf(x[f], fmaf(x[f], p.x, p.y), a);
        }
        #pragma unroll
        for (int f = 0; f < kFC; ++f) {
            a += lcat[rowdw[f] + c];
        }

        if (a >= thr) {
            // Exact reference numerics (validated, bit-identical sequence).
            const float* __restrict__ row = cat_probs + (size_t)c * (kFC * kV);
            float cat = row[pack[0] & 63];
            #pragma unroll
            for (int f = 1; f < kFC; ++f) {
                const int v = (pack[f >> 2] >> ((f & 3) * 8)) & 63;
                cat *= row[(f << 6) + v];
            }
            float num;
            #pragma unroll
            for (int f = 0; f < kFN; ++f) {
                float m = means[c * kFN + f];
                float s = stds [c * kFN + f];
                float inv = 1.0f / (two_pi * (s * s));
                float z = (x[f] - m) / s;              // IEEE divide
                float e = expf(-0.5f * (z * z));
                float lik = inv * e;
                num = (f == 0) ? lik : num * lik;
            }
            float pred = (class_probs[c] * cat) * num; // ((cp*cat)*num) like ref
            if (pred > bb) { bb = pred; bi = c; }      // strict > -> first max
        }
    }
    out[n] = bi;
}

extern "C" void kernel_launch(void* const* d_in, const int* in_sizes, int n_in,
                              void* d_out, int out_size, void* d_ws, size_t ws_size,
                              hipStream_t stream) {
    const int*   X_cat       = (const int*)  d_in[0];
    const float* X_num       = (const float*)d_in[1];
    const float* class_probs = (const float*)d_in[2];
    const float* cat_probs   = (const float*)d_in[3];
    const float* means       = (const float*)d_in[4];
    const float* stds        = (const float*)d_in[5];
    int*   out = (int*)d_out;
    float* ws  = (float*)d_ws;

    const int use_tab = (ws_size >= kWsNeedBytes) ? 1 : 0;

    hipLaunchKernelGGL(nbc_prep, dim3(use_tab ? 33 : 1), dim3(256), 0, stream,
                       class_probs, means, stds, cat_probs, ws, use_tab);

    dim3 block(kBlock);
    dim3 grid((kN + kBlock - 1) / kBlock);
    hipLaunchKernelGGL(nbc_main, grid, block, 0, stream,
                       X_cat, X_num, class_probs, cat_probs, means, stds, ws,
                       out, use_tab);
}